// Round 1
// 2628.480 us; speedup vs baseline: 5.9607x; 5.9607x over previous
//
#include <hip/hip_runtime.h>
#include <hip/hip_bf16.h>

// n=4, c=512, h=w=64. Runtime dtype via detect_f32 (R3-proven).
#define NBATCH 4
#define C 512
#define HW 4096
#define GROUPS 32
#define EPSV 1e-5f
#define ATTN_SCALE 0.044194173824159216f  // 1/sqrt(512)

typedef short bf16x8 __attribute__((ext_vector_type(8)));  // 8 bf16 = 4 VGPR
typedef float f32x4 __attribute__((ext_vector_type(4)));

__device__ __forceinline__ float bf(unsigned short u) {
  return __uint_as_float(((unsigned)u) << 16);
}
__device__ __forceinline__ unsigned short fb(float v) {
  __hip_bfloat16 h = __float2bfloat16(v);
  return *(unsigned short*)&h;
}
__device__ __forceinline__ bf16x8 frag_ld(const short* p) {
  return *(const bf16x8*)p;  // 16B-aligned by construction
}
#define MFMA(a, b, c) __builtin_amdgcn_mfma_f32_16x16x32_bf16((a), (b), (c), 0, 0, 0)

__device__ __forceinline__ void unpack8(uint4 w, float* f) {
  f[0] = __uint_as_float(w.x << 16);
  f[1] = __uint_as_float(w.x & 0xFFFF0000u);
  f[2] = __uint_as_float(w.y << 16);
  f[3] = __uint_as_float(w.y & 0xFFFF0000u);
  f[4] = __uint_as_float(w.z << 16);
  f[5] = __uint_as_float(w.z & 0xFFFF0000u);
  f[6] = __uint_as_float(w.w << 16);
  f[7] = __uint_as_float(w.w & 0xFFFF0000u);
}

// Runtime dtype detection (R3-proven).
__device__ __forceinline__ bool detect_f32(const void* w_in) {
  const unsigned short* u = (const unsigned short*)w_in;
  bool f32 = false;
#pragma unroll
  for (int i = 0; i < 64; ++i) {
    float v = bf(u[i]);
    if (!(fabsf(v) < 1e3f)) f32 = true;  // NaN -> true
  }
  return f32;
}
__device__ __forceinline__ float ld(const void* p, size_t i, bool f32) {
  if (f32) return ((const float*)p)[i];
  return bf(((const unsigned short*)p)[i]);
}

// Load an MFMA A-fragment (8 contiguous k-elements) from a weight matrix of
// either dtype. off is in elements.
__device__ __forceinline__ bf16x8 wfrag(const void* w, size_t off, bool f32) {
  if (f32) {
    const float4* p = (const float4*)((const float*)w + off);
    float4 w0 = p[0], w1 = p[1];
    bf16x8 r;
    r[0] = (short)fb(w0.x); r[1] = (short)fb(w0.y);
    r[2] = (short)fb(w0.z); r[3] = (short)fb(w0.w);
    r[4] = (short)fb(w1.x); r[5] = (short)fb(w1.y);
    r[6] = (short)fb(w1.z); r[7] = (short)fb(w1.w);
    return r;
  }
  return frag_ld((const short*)w + off);
}

// Stage GN-normalized x rows [t0, t0+32) into xn[32][520] (bf16), layout
// [row][c]. Verbatim logic from the R3-proven kv_gemm staging.
__device__ __forceinline__ void stage_xn(short* xn, const void* x,
                                         const void* gsc, const void* gbi,
                                         const float* stats, int nn, int t0,
                                         bool f32) {
  const int tid = threadIdx.x;
  const int part = tid & 3, crel = tid >> 2;
  for (int c0 = 0; c0 < 512; c0 += 64) {
    int c = c0 + crel;
    float rr = stats[128 + nn * GROUPS + (c >> 4)];
    float mu = stats[nn * GROUPS + (c >> 4)];
    float scl = ld(gsc, c, f32) * rr;
    float sft = ld(gbi, c, f32) - mu * scl;
    float f[8];
    if (f32) {
      const float4* p = (const float4*)((const float*)x +
                                        ((size_t)(nn * C + c) << 12) + t0 + part * 8);
      float4 r0 = p[0], r1 = p[1];
      f[0] = r0.x; f[1] = r0.y; f[2] = r0.z; f[3] = r0.w;
      f[4] = r1.x; f[5] = r1.y; f[6] = r1.z; f[7] = r1.w;
    } else {
      uint4 raw = *(const uint4*)((const unsigned short*)x +
                                  ((size_t)(nn * C + c) << 12) + t0 + part * 8);
      unpack8(raw, f);
    }
#pragma unroll
    for (int j = 0; j < 8; ++j)
      xn[(part * 8 + j) * 520 + c] = (short)fb(f[j] * scl + sft);
  }
}

// ---------------------------------------------------------------------------
// GroupNorm stats — R3-proven verbatim. stats[0:128)=mean, [128:256)=rstd.
// ---------------------------------------------------------------------------
__global__ __launch_bounds__(256) void gn_stats_kernel(
    const void* __restrict__ x, const void* __restrict__ w_in,
    float* __restrict__ stats) {
  const bool f32 = detect_f32(w_in);
  const int b = blockIdx.x;
  const size_t base = (size_t)b << 16;
  float s = 0.f, ss = 0.f;
  for (int i = threadIdx.x; i < 65536; i += 256) {
    float v = ld(x, base + i, f32);
    s += v;
    ss += v * v;
  }
  __shared__ float rs[256], rq[256];
  rs[threadIdx.x] = s;
  rq[threadIdx.x] = ss;
  __syncthreads();
  for (int off = 128; off > 0; off >>= 1) {
    if (threadIdx.x < off) {
      rs[threadIdx.x] += rs[threadIdx.x + off];
      rq[threadIdx.x] += rq[threadIdx.x + off];
    }
    __syncthreads();
  }
  if (threadIdx.x == 0) {
    float m = rs[0] * (1.0f / 65536.0f);
    float var = rq[0] * (1.0f / 65536.0f) - m * m;
    stats[b] = m;
    stats[128 + b] = rsqrtf(var + EPSV);
  }
}

// ---------------------------------------------------------------------------
// kv_gemm — proven MFMA layout; epilogue now writes:
//   K: kbuf[t][e]   (bf16, row stride 512)
//   V: vT[e][t]     (bf16, TRANSPOSED so PV B-frags are 16B-contiguous in t)
// grid (4, 128, Z): bx = proj*2 + ehalf (proj 0=K,1=V); by = 32-row t tile;
// bz = batch slot (concurrent mode) / 0 (fallback).
// ---------------------------------------------------------------------------
__global__ __launch_bounds__(256) void kv_gemm_kernel(
    const void* __restrict__ x, const void* __restrict__ gsc,
    const void* __restrict__ gbi, const float* __restrict__ stats,
    const void* __restrict__ w_in, const void* __restrict__ b_in,
    unsigned short* __restrict__ kvbase, int nn0) {
  const bool f32 = detect_f32(w_in);
  const int nn = nn0 + blockIdx.z;
  unsigned short* kbuf = kvbase + (size_t)blockIdx.z * 4194304;
  unsigned short* vT = kbuf + 2097152;
  __shared__ __align__(16) short xn[32 * 520];
  const int tid = threadIdx.x;
  const int wave = tid >> 6, lane = tid & 63, l15 = lane & 15, quad = lane >> 4;
  const int t0 = blockIdx.y * 32;
  const int proj = blockIdx.x >> 1;  // 0 = K, 1 = V
  const int ehalf = blockIdx.x & 1;

  stage_xn(xn, x, gsc, gbi, stats, nn, t0, f32);
  __syncthreads();

  const int wrow = 512 + proj * 512 + ehalf * 256 + wave * 64;  // w_in row
  const int cbase = ehalf * 256 + wave * 64;                    // col in [0,512)

  f32x4 acc[4][2];
#pragma unroll
  for (int i = 0; i < 4; ++i) {
    acc[i][0] = {0.f, 0.f, 0.f, 0.f};
    acc[i][1] = {0.f, 0.f, 0.f, 0.f};
  }

  for (int kc = 0; kc < 16; ++kc) {
    bf16x8 b0f = frag_ld(xn + l15 * 520 + kc * 32 + quad * 8);
    bf16x8 b1f = frag_ld(xn + (16 + l15) * 520 + kc * 32 + quad * 8);
#pragma unroll
    for (int es = 0; es < 4; ++es) {
      bf16x8 a = wfrag(w_in, (size_t)(wrow + es * 16 + l15) * 512 + kc * 32 + quad * 8, f32);
      acc[es][0] = MFMA(a, b0f, acc[es][0]);
      acc[es][1] = MFMA(a, b1f, acc[es][1]);
    }
  }

#pragma unroll
  for (int es = 0; es < 4; ++es) {
    int bidx = wrow + es * 16 + quad * 4;
    float b0 = ld(b_in, bidx, f32), b1 = ld(b_in, bidx + 1, f32);
    float b2 = ld(b_in, bidx + 2, f32), b3 = ld(b_in, bidx + 3, f32);
    int ecol = cbase + es * 16 + quad * 4;
#pragma unroll
    for (int ts = 0; ts < 2; ++ts) {
      int t = t0 + ts * 16 + l15;
      float v0 = acc[es][ts][0] + b0, v1 = acc[es][ts][1] + b1;
      float v2 = acc[es][ts][2] + b2, v3 = acc[es][ts][3] + b3;
      if (proj == 0) {
        uint2 u;
        u.x = (unsigned)fb(v0) | ((unsigned)fb(v1) << 16);
        u.y = (unsigned)fb(v2) | ((unsigned)fb(v3) << 16);
        *(uint2*)(kbuf + (size_t)t * 512 + ecol) = u;
      } else {
        vT[(size_t)(ecol + 0) * 4096 + t] = fb(v0);
        vT[(size_t)(ecol + 1) * 4096 + t] = fb(v1);
        vT[(size_t)(ecol + 2) * 4096 + t] = fb(v2);
        vT[(size_t)(ecol + 3) * 4096 + t] = fb(v3);
      }
    }
  }
}

// ---------------------------------------------------------------------------
// flash_kernel — replaces the scalar attn_proj (MfmaUtil was 0.0).
// One block = 32 query rows (t0..t0+32), 4 waves, fully MFMA:
//   GN-stage -> Q gemm -> flash K-loop (S=Q.K^T, online softmax, PV) ->
//   out-projection + bias + residual.
// Wave w owns O columns [w*128, w*128+128); all waves redundantly compute S.
// LDS: xn/Ktile union [32][520|512] | Qs [32][520] | P 4x[32][56]  = 79 KB
//   -> 2 blocks/CU. Ktile XOR-swizzled (byte^=(row&7)<<4) to kill the
//   16-way stride-1KB ds_read_b128 bank conflict (G4).
// ---------------------------------------------------------------------------
__global__ __launch_bounds__(256, 2) void flash_kernel(
    const void* __restrict__ x, const void* __restrict__ gsc,
    const void* __restrict__ gbi, const float* __restrict__ stats,
    const void* __restrict__ w_in, const void* __restrict__ b_in,
    const unsigned short* __restrict__ kvbase,
    const void* __restrict__ w_out, const void* __restrict__ b_out,
    void* __restrict__ out, int nn0) {
  const bool f32 = detect_f32(w_in);
  const int nn = nn0 + blockIdx.z;
  const unsigned short* kbuf = kvbase + (size_t)blockIdx.z * 4194304;
  const unsigned short* vT = kbuf + 2097152;

  __shared__ __align__(16) short lds[16640 + 16640 + 4 * 32 * 56];
  short* xn = lds;        // [32][520]; reused as Ktile [32][512] and O buffer
  short* Ktile = lds;
  short* Qs = lds + 16640;  // [32][520] bf16, Q pre-scaled by ATTN_SCALE
  const int tid = threadIdx.x;
  const int wave = tid >> 6, lane = tid & 63, l15 = lane & 15, quad = lane >> 4;
  short* Pl = lds + 33280 + wave * (32 * 56);  // per-wave P [32][56]
  const int t0 = blockIdx.x * 32;

  // ---- stage GN-normalized query rows ----
  stage_xn(xn, x, gsc, gbi, stats, nn, t0, f32);
  __syncthreads();

  // ---- Q gemm: wave computes Q[t=0..32)[e in wave*128..+128) ----
  f32x4 qacc[8][2];
#pragma unroll
  for (int i = 0; i < 8; ++i) {
    qacc[i][0] = {0.f, 0.f, 0.f, 0.f};
    qacc[i][1] = {0.f, 0.f, 0.f, 0.f};
  }
  for (int kc = 0; kc < 16; ++kc) {
    bf16x8 bx0 = frag_ld(xn + l15 * 520 + kc * 32 + quad * 8);
    bf16x8 bx1 = frag_ld(xn + (16 + l15) * 520 + kc * 32 + quad * 8);
#pragma unroll
    for (int es = 0; es < 8; ++es) {
      bf16x8 a = wfrag(w_in, (size_t)(wave * 128 + es * 16 + l15) * 512 + kc * 32 + quad * 8, f32);
      qacc[es][0] = MFMA(a, bx0, qacc[es][0]);
      qacc[es][1] = MFMA(a, bx1, qacc[es][1]);
    }
  }
  // D[m=e][n=t] -> Qs[t][e] = (acc + b_in[e]) * ATTN_SCALE   (bf16)
#pragma unroll
  for (int es = 0; es < 8; ++es) {
    int e0 = wave * 128 + es * 16 + quad * 4;
    float b0 = ld(b_in, e0, f32), b1 = ld(b_in, e0 + 1, f32);
    float b2 = ld(b_in, e0 + 2, f32), b3 = ld(b_in, e0 + 3, f32);
#pragma unroll
    for (int ts = 0; ts < 2; ++ts) {
      int t = ts * 16 + l15;
      uint2 u;
      u.x = (unsigned)fb((qacc[es][ts][0] + b0) * ATTN_SCALE) |
            ((unsigned)fb((qacc[es][ts][1] + b1) * ATTN_SCALE) << 16);
      u.y = (unsigned)fb((qacc[es][ts][2] + b2) * ATTN_SCALE) |
            ((unsigned)fb((qacc[es][ts][3] + b3) * ATTN_SCALE) << 16);
      *(uint2*)(Qs + t * 520 + e0) = u;
    }
  }

  // preload K tile 0 into registers (wave stages rows wave*8..+8, 16B/lane)
  bf16x8 kreg[8];
#pragma unroll
  for (int r8 = 0; r8 < 8; ++r8)
    kreg[r8] = frag_ld((const short*)kbuf + (size_t)(wave * 8 + r8) * 512 + lane * 8);

  f32x4 o[2][8];
#pragma unroll
  for (int rt = 0; rt < 2; ++rt)
#pragma unroll
    for (int oc = 0; oc < 8; ++oc) o[rt][oc] = {0.f, 0.f, 0.f, 0.f};
  float mrow[2][4], lrow[2][4], scl[2][4];
#pragma unroll
  for (int rt = 0; rt < 2; ++rt)
#pragma unroll
    for (int r = 0; r < 4; ++r) {
      mrow[rt][r] = -3.0e38f;
      lrow[rt][r] = 0.f;
    }

  __syncthreads();  // Qs visible to all waves; xn region free for Ktile

// online-softmax row update for one 16-row tile (rows = rt*16+quad*4+r);
// row-reduce over the 16 l15 lanes via shfl_xor (wave-parallel, G5)
#define SOFTMAX_RT(rt, sa, sb)                                  \
  {                                                             \
    _Pragma("unroll") for (int r = 0; r < 4; ++r) {             \
      float v = fmaxf(sa[r], sb[r]);                            \
      v = fmaxf(v, __shfl_xor(v, 1));                           \
      v = fmaxf(v, __shfl_xor(v, 2));                           \
      v = fmaxf(v, __shfl_xor(v, 4));                           \
      v = fmaxf(v, __shfl_xor(v, 8));                           \
      float mold = mrow[rt][r];                                 \
      float mnew = fmaxf(mold, v);                              \
      float sc = __expf(mold - mnew);                           \
      float pa = __expf(sa[r] - mnew);                          \
      float pb = __expf(sb[r] - mnew);                          \
      sa[r] = pa;                                               \
      sb[r] = pb;                                               \
      float rs = pa + pb;                                       \
      rs += __shfl_xor(rs, 1);                                  \
      rs += __shfl_xor(rs, 2);                                  \
      rs += __shfl_xor(rs, 4);                                  \
      rs += __shfl_xor(rs, 8);                                  \
      lrow[rt][r] = lrow[rt][r] * sc + rs;                      \
      mrow[rt][r] = mnew;                                       \
      scl[rt][r] = sc;                                          \
    }                                                           \
  }

  for (int tk = 0; tk < 128; ++tk) {
    // ds_write staged K rows, XOR-swizzled granule (lane ^ row&7)
#pragma unroll
    for (int r8 = 0; r8 < 8; ++r8)
      *(bf16x8*)(Ktile + (wave * 8 + r8) * 512 + ((lane ^ r8) * 8)) = kreg[r8];
    __syncthreads();
    // T14: issue next tile's global loads now; they retire under the MFMAs
    if (tk < 127) {
      const short* src = (const short*)kbuf + (size_t)(tk + 1) * 32 * 512;
#pragma unroll
      for (int r8 = 0; r8 < 8; ++r8)
        kreg[r8] = frag_ld(src + (size_t)(wave * 8 + r8) * 512 + lane * 8);
    }

    // ---- S = Q @ K^T : D[m=qrow][n=tcol], full k=512 per wave ----
    f32x4 s00 = {0.f, 0.f, 0.f, 0.f}, s01 = {0.f, 0.f, 0.f, 0.f};
    f32x4 s10 = {0.f, 0.f, 0.f, 0.f}, s11 = {0.f, 0.f, 0.f, 0.f};
#pragma unroll
    for (int kc = 0; kc < 16; ++kc) {
      const int ko = kc * 32 + quad * 8;
      bf16x8 qa0 = frag_ld(Qs + l15 * 520 + ko);
      bf16x8 qa1 = frag_ld(Qs + (16 + l15) * 520 + ko);
      const int ksw = ko ^ ((l15 & 7) << 3);  // inverse of staging swizzle
      bf16x8 kb0 = frag_ld(Ktile + l15 * 512 + ksw);
      bf16x8 kb1 = frag_ld(Ktile + (16 + l15) * 512 + ksw);
      s00 = MFMA(qa0, kb0, s00);
      s01 = MFMA(qa0, kb1, s01);
      s10 = MFMA(qa1, kb0, s10);
      s11 = MFMA(qa1, kb1, s11);
    }

    // ---- online softmax (in-register, identical across waves) ----
    SOFTMAX_RT(0, s00, s01)
    SOFTMAX_RT(1, s10, s11)

    // P (bf16) -> per-wave LDS [qrow][t], stride 56
#pragma unroll
    for (int r = 0; r < 4; ++r) {
      int ra = quad * 4 + r, rb = 16 + quad * 4 + r;
      Pl[ra * 56 + l15] = (short)fb(s00[r]);
      Pl[ra * 56 + 16 + l15] = (short)fb(s01[r]);
      Pl[rb * 56 + l15] = (short)fb(s10[r]);
      Pl[rb * 56 + 16 + l15] = (short)fb(s11[r]);
    }
    // rescale O accumulator by exp(mold-mnew) before adding this tile
#pragma unroll
    for (int oc = 0; oc < 8; ++oc)
#pragma unroll
      for (int r = 0; r < 4; ++r) {
        o[0][oc][r] *= scl[0][r];
        o[1][oc][r] *= scl[1][r];
      }

    // ---- PV: O[qrow][vcol] += P @ V, V read transposed from vT ----
    {
      bf16x8 pa0 = frag_ld(Pl + l15 * 56 + quad * 8);
      bf16x8 pa1 = frag_ld(Pl + (16 + l15) * 56 + quad * 8);
      const unsigned short* vb0 =
          vT + (size_t)(wave * 128) * 4096 + (size_t)tk * 32 + quad * 8;
#pragma unroll
      for (int oc = 0; oc < 8; ++oc) {
        bf16x8 vb = frag_ld((const short*)(vb0 + (size_t)(oc * 16 + l15) * 4096));
        o[0][oc] = MFMA(pa0, vb, o[0][oc]);
        o[1][oc] = MFMA(pa1, vb, o[1][oc]);
      }
    }
    __syncthreads();  // all waves done reading Ktile before next overwrite
  }

  // ---- normalize O and park it (bf16) in xn [32][520] ----
#pragma unroll
  for (int rt = 0; rt < 2; ++rt)
#pragma unroll
    for (int r = 0; r < 4; ++r) {
      float inv = 1.0f / lrow[rt][r];
      int row = rt * 16 + quad * 4 + r;
#pragma unroll
      for (int oc = 0; oc < 8; ++oc)
        xn[row * 520 + wave * 128 + oc * 16 + l15] = (short)fb(o[rt][oc][r] * inv);
    }
  __syncthreads();

  // ---- out-projection: D[m=cc][n=t] = O @ w_out^T ----
  f32x4 oacc[8][2];
#pragma unroll
  for (int i = 0; i < 8; ++i) {
    oacc[i][0] = {0.f, 0.f, 0.f, 0.f};
    oacc[i][1] = {0.f, 0.f, 0.f, 0.f};
  }
  for (int kc = 0; kc < 16; ++kc) {
    bf16x8 bx0 = frag_ld(xn + l15 * 520 + kc * 32 + quad * 8);
    bf16x8 bx1 = frag_ld(xn + (16 + l15) * 520 + kc * 32 + quad * 8);
#pragma unroll
    for (int es = 0; es < 8; ++es) {
      bf16x8 a = wfrag(w_out, (size_t)(wave * 128 + es * 16 + l15) * 512 + kc * 32 + quad * 8, f32);
      oacc[es][0] = MFMA(a, bx0, oacc[es][0]);
      oacc[es][1] = MFMA(a, bx1, oacc[es][1]);
    }
  }
  // bias + residual + store
#pragma unroll
  for (int es = 0; es < 8; ++es) {
    int cc = wave * 128 + es * 16 + quad * 4;
    float b0 = ld(b_out, cc, f32), b1 = ld(b_out, cc + 1, f32);
    float b2 = ld(b_out, cc + 2, f32), b3 = ld(b_out, cc + 3, f32);
#pragma unroll
    for (int ts = 0; ts < 2; ++ts) {
      int t = t0 + ts * 16 + l15;
      float vv0 = oacc[es][ts][0] + b0, vv1 = oacc[es][ts][1] + b1;
      float vv2 = oacc[es][ts][2] + b2, vv3 = oacc[es][ts][3] + b3;
      float vr[4] = {vv0, vv1, vv2, vv3};
#pragma unroll
      for (int r = 0; r < 4; ++r) {
        size_t oidx = ((size_t)(nn * C + cc + r) << 12) + t;
        float v = vr[r] + ld(x, oidx, f32);
        if (f32)
          ((float*)out)[oidx] = v;
        else
          ((unsigned short*)out)[oidx] = fb(v);
      }
    }
  }
}

// ---------------------------------------------------------------------------
extern "C" void kernel_launch(void* const* d_in, const int* in_sizes, int n_in,
                              void* d_out, int out_size, void* d_ws, size_t ws_size,
                              hipStream_t stream) {
  const void* x = d_in[0];
  const void* gn_scale = d_in[1];
  const void* gn_bias = d_in[2];
  const void* w_in = d_in[3];
  const void* b_in = d_in[4];
  const void* w_out = d_in[5];
  const void* b_out = d_in[6];
  (void)in_sizes; (void)n_in; (void)out_size;

  // ws: [stats 1KB | per-batch slot: K bf16 4096x512 + vT bf16 512x4096]
  // slot = 8 MB. Concurrent 4-batch mode needs 33.6 MB; fallback uses the
  // R3-proven 8.39 MB footprint with a host-side batch loop.
  float* stats = (float*)d_ws;
  unsigned short* kv0 = (unsigned short*)((char*)d_ws + 1024);
  const size_t need4 = 1024 + (size_t)4 * 4194304 * 2;

  gn_stats_kernel<<<NBATCH * GROUPS, 256, 0, stream>>>(x, w_in, stats);

  if (ws_size >= need4) {
    kv_gemm_kernel<<<dim3(4, 128, 4), 256, 0, stream>>>(
        x, gn_scale, gn_bias, stats, w_in, b_in, kv0, 0);
    flash_kernel<<<dim3(128, 1, 4), 256, 0, stream>>>(
        x, gn_scale, gn_bias, stats, w_in, b_in, kv0, w_out, b_out, d_out, 0);
  } else {
    for (int nn = 0; nn < NBATCH; ++nn) {
      kv_gemm_kernel<<<dim3(4, 128, 1), 256, 0, stream>>>(
          x, gn_scale, gn_bias, stats, w_in, b_in, kv0, nn);
      flash_kernel<<<dim3(128, 1, 1), 256, 0, stream>>>(
          x, gn_scale, gn_bias, stats, w_in, b_in, kv0, w_out, b_out, d_out, nn);
    }
  }
}

// Round 2
// 1064.159 us; speedup vs baseline: 14.7229x; 2.4700x over previous
//
#include <hip/hip_runtime.h>
#include <hip/hip_bf16.h>

// n=4, c=512, h=w=64. Runtime dtype via detect_f32 (R3-proven).
#define NBATCH 4
#define C 512
#define HW 4096
#define GROUPS 32
#define EPSV 1e-5f
#define ATTN_SCALE 0.044194173824159216f  // 1/sqrt(512)

typedef short bf16x8 __attribute__((ext_vector_type(8)));  // 8 bf16 = 4 VGPR
typedef float f32x4 __attribute__((ext_vector_type(4)));

__device__ __forceinline__ float bf(unsigned short u) {
  return __uint_as_float(((unsigned)u) << 16);
}
__device__ __forceinline__ unsigned short fb(float v) {
  __hip_bfloat16 h = __float2bfloat16(v);
  return *(unsigned short*)&h;
}
__device__ __forceinline__ bf16x8 frag_ld(const short* p) {
  return *(const bf16x8*)p;  // 16B-aligned by construction
}
#define MFMA(a, b, c) __builtin_amdgcn_mfma_f32_16x16x32_bf16((a), (b), (c), 0, 0, 0)

#define SCHED_FENCE() __builtin_amdgcn_sched_barrier(0)
// raw barrier (NO vmcnt drain) + compiler/scheduler fences (rule #18 / m152)
#define BAR()                                   \
  do {                                          \
    asm volatile("" ::: "memory");              \
    SCHED_FENCE();                              \
    __builtin_amdgcn_s_barrier();               \
    SCHED_FENCE();                              \
    asm volatile("" ::: "memory");              \
  } while (0)
#define WAITV(N)                                                  \
  do {                                                            \
    asm volatile("s_waitcnt vmcnt(" #N ")" ::: "memory");         \
    SCHED_FENCE();                                                \
  } while (0)

// async global->LDS, 16B per lane; LDS dest is wave-uniform base + lane*16
__device__ __forceinline__ void gl_lds16(const short* g, short* l) {
  __builtin_amdgcn_global_load_lds(
      (const __attribute__((address_space(1))) unsigned int*)g,
      (__attribute__((address_space(3))) unsigned int*)l, 16, 0, 0);
}

__device__ __forceinline__ void unpack8(uint4 w, float* f) {
  f[0] = __uint_as_float(w.x << 16);
  f[1] = __uint_as_float(w.x & 0xFFFF0000u);
  f[2] = __uint_as_float(w.y << 16);
  f[3] = __uint_as_float(w.y & 0xFFFF0000u);
  f[4] = __uint_as_float(w.z << 16);
  f[5] = __uint_as_float(w.z & 0xFFFF0000u);
  f[6] = __uint_as_float(w.w << 16);
  f[7] = __uint_as_float(w.w & 0xFFFF0000u);
}

// Runtime dtype detection (R3-proven).
__device__ __forceinline__ bool detect_f32(const void* w_in) {
  const unsigned short* u = (const unsigned short*)w_in;
  bool f32 = false;
#pragma unroll
  for (int i = 0; i < 64; ++i) {
    float v = bf(u[i]);
    if (!(fabsf(v) < 1e3f)) f32 = true;  // NaN -> true
  }
  return f32;
}
__device__ __forceinline__ float ld(const void* p, size_t i, bool f32) {
  if (f32) return ((const float*)p)[i];
  return bf(((const unsigned short*)p)[i]);
}

// MFMA A-fragment (8 contiguous k-elements) from a weight matrix, either dtype.
__device__ __forceinline__ bf16x8 wfrag(const void* w, size_t off, bool f32) {
  if (f32) {
    const float4* p = (const float4*)((const float*)w + off);
    float4 w0 = p[0], w1 = p[1];
    bf16x8 r;
    r[0] = (short)fb(w0.x); r[1] = (short)fb(w0.y);
    r[2] = (short)fb(w0.z); r[3] = (short)fb(w0.w);
    r[4] = (short)fb(w1.x); r[5] = (short)fb(w1.y);
    r[6] = (short)fb(w1.z); r[7] = (short)fb(w1.w);
    return r;
  }
  return frag_ld((const short*)w + off);
}

// Stage GN-normalized x rows [t0, t0+32) into xn[32][520] (bf16). R3-proven.
__device__ __forceinline__ void stage_xn(short* xn, const void* x,
                                         const void* gsc, const void* gbi,
                                         const float* stats, int nn, int t0,
                                         bool f32) {
  const int tid = threadIdx.x;
  const int part = tid & 3, crel = tid >> 2;
  for (int c0 = 0; c0 < 512; c0 += 64) {
    int c = c0 + crel;
    float rr = stats[128 + nn * GROUPS + (c >> 4)];
    float mu = stats[nn * GROUPS + (c >> 4)];
    float scl = ld(gsc, c, f32) * rr;
    float sft = ld(gbi, c, f32) - mu * scl;
    float f[8];
    if (f32) {
      const float4* p = (const float4*)((const float*)x +
                                        ((size_t)(nn * C + c) << 12) + t0 + part * 8);
      float4 r0 = p[0], r1 = p[1];
      f[0] = r0.x; f[1] = r0.y; f[2] = r0.z; f[3] = r0.w;
      f[4] = r1.x; f[5] = r1.y; f[6] = r1.z; f[7] = r1.w;
    } else {
      uint4 raw = *(const uint4*)((const unsigned short*)x +
                                  ((size_t)(nn * C + c) << 12) + t0 + part * 8);
      unpack8(raw, f);
    }
#pragma unroll
    for (int j = 0; j < 8; ++j)
      xn[(part * 8 + j) * 520 + c] = (short)fb(f[j] * scl + sft);
  }
}

// ---------------------------------------------------------------------------
// GroupNorm stats — R3-proven verbatim.
// ---------------------------------------------------------------------------
__global__ __launch_bounds__(256) void gn_stats_kernel(
    const void* __restrict__ x, const void* __restrict__ w_in,
    float* __restrict__ stats) {
  const bool f32 = detect_f32(w_in);
  const int b = blockIdx.x;
  const size_t base = (size_t)b << 16;
  float s = 0.f, ss = 0.f;
  for (int i = threadIdx.x; i < 65536; i += 256) {
    float v = ld(x, base + i, f32);
    s += v;
    ss += v * v;
  }
  __shared__ float rs[256], rq[256];
  rs[threadIdx.x] = s;
  rq[threadIdx.x] = ss;
  __syncthreads();
  for (int off = 128; off > 0; off >>= 1) {
    if (threadIdx.x < off) {
      rs[threadIdx.x] += rs[threadIdx.x + off];
      rq[threadIdx.x] += rq[threadIdx.x + off];
    }
    __syncthreads();
  }
  if (threadIdx.x == 0) {
    float m = rs[0] * (1.0f / 65536.0f);
    float var = rq[0] * (1.0f / 65536.0f) - m * m;
    stats[b] = m;
    stats[128 + b] = rsqrtf(var + EPSV);
  }
}

// ---------------------------------------------------------------------------
// kv_gemm — proven MFMA core. Epilogue now writes:
//   K: kbuf[t][col] PRE-SWIZZLED: logical col granule g=e>>3 stored at
//      granule g^(t&7)  (so flash can global_load_lds linearly and read
//      ds_read_b128 bank-conflict-free).
//   V: vbuf tiled [tk][e][t&31]  (tile = 32KB contiguous -> linear stage).
// ---------------------------------------------------------------------------
__global__ __launch_bounds__(256) void kv_gemm_kernel(
    const void* __restrict__ x, const void* __restrict__ gsc,
    const void* __restrict__ gbi, const float* __restrict__ stats,
    const void* __restrict__ w_in, const void* __restrict__ b_in,
    unsigned short* __restrict__ kvbase, int nn0) {
  const bool f32 = detect_f32(w_in);
  const int nn = nn0 + blockIdx.z;
  unsigned short* kbuf = kvbase + (size_t)blockIdx.z * 4194304;
  unsigned short* vbuf = kbuf + 2097152;
  __shared__ __align__(16) short xn[32 * 520];
  const int tid = threadIdx.x;
  const int wave = tid >> 6, lane = tid & 63, l15 = lane & 15, quad = lane >> 4;
  const int t0 = blockIdx.y * 32;
  const int proj = blockIdx.x >> 1;  // 0 = K, 1 = V
  const int ehalf = blockIdx.x & 1;

  stage_xn(xn, x, gsc, gbi, stats, nn, t0, f32);
  __syncthreads();

  const int wrow = 512 + proj * 512 + ehalf * 256 + wave * 64;  // w_in row
  const int cbase = ehalf * 256 + wave * 64;                    // col in [0,512)

  f32x4 acc[4][2];
#pragma unroll
  for (int i = 0; i < 4; ++i) {
    acc[i][0] = {0.f, 0.f, 0.f, 0.f};
    acc[i][1] = {0.f, 0.f, 0.f, 0.f};
  }

  for (int kc = 0; kc < 16; ++kc) {
    bf16x8 b0f = frag_ld(xn + l15 * 520 + kc * 32 + quad * 8);
    bf16x8 b1f = frag_ld(xn + (16 + l15) * 520 + kc * 32 + quad * 8);
#pragma unroll
    for (int es = 0; es < 4; ++es) {
      bf16x8 a = wfrag(w_in, (size_t)(wrow + es * 16 + l15) * 512 + kc * 32 + quad * 8, f32);
      acc[es][0] = MFMA(a, b0f, acc[es][0]);
      acc[es][1] = MFMA(a, b1f, acc[es][1]);
    }
  }

#pragma unroll
  for (int es = 0; es < 4; ++es) {
    int bidx = wrow + es * 16 + quad * 4;
    float b0 = ld(b_in, bidx, f32), b1 = ld(b_in, bidx + 1, f32);
    float b2 = ld(b_in, bidx + 2, f32), b3 = ld(b_in, bidx + 3, f32);
    int ecol = cbase + es * 16 + quad * 4;
#pragma unroll
    for (int ts = 0; ts < 2; ++ts) {
      int t = t0 + ts * 16 + l15;
      float v0 = acc[es][ts][0] + b0, v1 = acc[es][ts][1] + b1;
      float v2 = acc[es][ts][2] + b2, v3 = acc[es][ts][3] + b3;
      if (proj == 0) {
        int sw = (((ecol >> 3) ^ (t & 7)) << 3) | (ecol & 7);
        uint2 u;
        u.x = (unsigned)fb(v0) | ((unsigned)fb(v1) << 16);
        u.y = (unsigned)fb(v2) | ((unsigned)fb(v3) << 16);
        *(uint2*)(kbuf + (size_t)t * 512 + sw) = u;
      } else {
        size_t tb = (size_t)(t >> 5) * 16384 + (t & 31);
        vbuf[tb + (size_t)(ecol + 0) * 32] = fb(v0);
        vbuf[tb + (size_t)(ecol + 1) * 32] = fb(v1);
        vbuf[tb + (size_t)(ecol + 2) * 32] = fb(v2);
        vbuf[tb + (size_t)(ecol + 3) * 32] = fb(v3);
      }
    }
  }
}

// ---------------------------------------------------------------------------
// flash64 — 64 q-rows/block, 4 waves, NO redundant S work.
// Wave w owns q-rows [w*16,w*16+16) (Q in 64 VGPRs) x full 512 O-cols
// (O in 128 VGPRs). K tile [32][512] staged via global_load_lds from the
// pre-swizzled kbuf into region A; V tile [512 e][32 t] staged linearly from
// tiled vbuf into region B. Counted vmcnt(8) + raw s_barrier: K(tk+1) flies
// under softmax+PV, V(tk+1) under next S (T3/T4). P transpose per-wave LDS.
// LDS 71.7KB -> 2 blocks/CU. Grid 256: batch b clustered on XCDs {2b,2b+1}.
// ---------------------------------------------------------------------------
__global__ __launch_bounds__(256, 2) void flash64_kernel(
    const void* __restrict__ x, const void* __restrict__ gsc,
    const void* __restrict__ gbi, const float* __restrict__ stats,
    const void* __restrict__ w_in, const void* __restrict__ b_in,
    const unsigned short* __restrict__ kvbase,
    const void* __restrict__ w_out, const void* __restrict__ b_out,
    void* __restrict__ out, int nn0, int conc) {
  const bool f32 = detect_f32(w_in);
  int nn, t0, slot;
  if (conc) {
    int xcd = blockIdx.x & 7;
    nn = xcd >> 1;
    slot = nn;
    t0 = ((((xcd & 1) << 5) | (blockIdx.x >> 3))) << 6;
  } else {
    nn = nn0; slot = 0; t0 = blockIdx.x << 6;
  }
  const unsigned short* kbuf = kvbase + (size_t)slot * 4194304;
  const unsigned short* vbuf = kbuf + 2097152;

  __shared__ __align__(16) short lds[35840];  // 71680 B
  short* RA = lds;                 // xn (Q phase) -> Ktile -> Os[0:]
  short* RB = lds + 16640;         // Qs (Q phase) -> Vs   -> Os[..]
  const int tid = threadIdx.x;
  const int wave = tid >> 6, lane = tid & 63, l15 = lane & 15, quad = lane >> 4;
  short* Pl = lds + 33280 + wave * 640;  // per-wave P [16][40]

  // ================= Q phase: two 32-row halves =================
  bf16x8 q[16];  // wave's 16 q-rows x 512 k, A-frag layout
  for (int h = 0; h < 2; ++h) {
    stage_xn(RA, x, gsc, gbi, stats, nn, t0 + h * 32, f32);
    __syncthreads();
    f32x4 qacc[8][2];
#pragma unroll
    for (int i = 0; i < 8; ++i) {
      qacc[i][0] = {0.f, 0.f, 0.f, 0.f};
      qacc[i][1] = {0.f, 0.f, 0.f, 0.f};
    }
    for (int kc = 0; kc < 16; ++kc) {
      bf16x8 bx0 = frag_ld(RA + l15 * 520 + kc * 32 + quad * 8);
      bf16x8 bx1 = frag_ld(RA + (16 + l15) * 520 + kc * 32 + quad * 8);
#pragma unroll
      for (int es = 0; es < 8; ++es) {
        bf16x8 a = wfrag(w_in, (size_t)(wave * 128 + es * 16 + l15) * 512 + kc * 32 + quad * 8, f32);
        qacc[es][0] = MFMA(a, bx0, qacc[es][0]);
        qacc[es][1] = MFMA(a, bx1, qacc[es][1]);
      }
    }
    // D[m=e][n=t] -> Qs[t][e] = (acc + b_in[e]) * ATTN_SCALE (bf16)
#pragma unroll
    for (int es = 0; es < 8; ++es) {
      int e0 = wave * 128 + es * 16 + quad * 4;
      float b0 = ld(b_in, e0, f32), b1 = ld(b_in, e0 + 1, f32);
      float b2 = ld(b_in, e0 + 2, f32), b3 = ld(b_in, e0 + 3, f32);
#pragma unroll
      for (int ts = 0; ts < 2; ++ts) {
        int t = ts * 16 + l15;
        uint2 u;
        u.x = (unsigned)fb((qacc[es][ts][0] + b0) * ATTN_SCALE) |
              ((unsigned)fb((qacc[es][ts][1] + b1) * ATTN_SCALE) << 16);
        u.y = (unsigned)fb((qacc[es][ts][2] + b2) * ATTN_SCALE) |
              ((unsigned)fb((qacc[es][ts][3] + b3) * ATTN_SCALE) << 16);
        *(uint2*)(RB + t * 520 + e0) = u;
      }
    }
    __syncthreads();
    // waves of this half pull their Q rows into registers (A-frag layout)
    if ((wave >> 1) == h) {
      int rb = (wave & 1) * 16;
#pragma unroll
      for (int kc = 0; kc < 16; ++kc)
        q[kc] = frag_ld(RB + (rb + l15) * 520 + kc * 32 + quad * 8);
    }
    __syncthreads();
  }

// ================= K/V tile staging macros =================
// per wave: 8 x 1KB global_load_lds, linear copy of its quarter
#define STAGE_K(tk)                                                           \
  {                                                                           \
    const short* s_ = (const short*)kbuf + (size_t)(tk)*16384 + wave * 4096 + \
                      lane * 8;                                               \
    short* d_ = RA + wave * 4096;                                             \
    _Pragma("unroll") for (int i_ = 0; i_ < 8; ++i_)                          \
        gl_lds16(s_ + i_ * 512, d_ + i_ * 512);                               \
  }
#define STAGE_V(tk)                                                           \
  {                                                                           \
    const short* s_ = (const short*)vbuf + (size_t)(tk)*16384 + wave * 4096 + \
                      lane * 8;                                               \
    short* d_ = RB + wave * 4096;                                             \
    _Pragma("unroll") for (int i_ = 0; i_ < 8; ++i_)                          \
        gl_lds16(s_ + i_ * 512, d_ + i_ * 512);                               \
  }

  f32x4 o[32];
#pragma unroll
  for (int oc = 0; oc < 32; ++oc) o[oc] = {0.f, 0.f, 0.f, 0.f};
  float mrow[4], lrow[4];
#pragma unroll
  for (int r = 0; r < 4; ++r) {
    mrow[r] = -3.0e38f;
    lrow[r] = 0.f;
  }

  STAGE_K(0);
  STAGE_V(0);

  for (int tk = 0; tk < 128; ++tk) {
    WAITV(8);  // K(tk) landed (V(tk) may still fly)
    BAR();

    // ---- S = Qw(16x512) @ K^T(32x512): D[m=qrow][n=t] ----
    f32x4 s0 = {0.f, 0.f, 0.f, 0.f}, s1 = {0.f, 0.f, 0.f, 0.f};
#pragma unroll
    for (int kc = 0; kc < 16; ++kc) {
      int g = ((kc * 4 + quad) ^ (l15 & 7)) * 8;  // inverse of kbuf swizzle
      bf16x8 kb0 = frag_ld(RA + l15 * 512 + g);
      bf16x8 kb1 = frag_ld(RA + (16 + l15) * 512 + g);
      s0 = MFMA(q[kc], kb0, s0);
      s1 = MFMA(q[kc], kb1, s1);
    }
    BAR();  // all waves done reading Ktile
    if (tk < 127) STAGE_K(tk + 1);  // flies under softmax + PV

    // ---- online softmax over 32 t (16 l15 lanes x 2 regs) ----
    float pscl[4];
#pragma unroll
    for (int r = 0; r < 4; ++r) {
      float v = fmaxf(s0[r], s1[r]);
      v = fmaxf(v, __shfl_xor(v, 1));
      v = fmaxf(v, __shfl_xor(v, 2));
      v = fmaxf(v, __shfl_xor(v, 4));
      v = fmaxf(v, __shfl_xor(v, 8));
      float mold = mrow[r];
      float mnew = fmaxf(mold, v);
      float sc = __expf(mold - mnew);
      float pa = __expf(s0[r] - mnew);
      float pb = __expf(s1[r] - mnew);
      float rs = pa + pb;
      rs += __shfl_xor(rs, 1);
      rs += __shfl_xor(rs, 2);
      rs += __shfl_xor(rs, 4);
      rs += __shfl_xor(rs, 8);
      lrow[r] = lrow[r] * sc + rs;
      mrow[r] = mnew;
      pscl[r] = sc;
      int row = quad * 4 + r;
      Pl[row * 40 + l15] = (short)fb(pa);
      Pl[row * 40 + 16 + l15] = (short)fb(pb);
    }
    // rescale O by exp(mold-mnew)
#pragma unroll
    for (int oc = 0; oc < 32; ++oc) {
#pragma unroll
      for (int r = 0; r < 4; ++r) o[oc][r] *= pscl[r];
    }
    bf16x8 pa = frag_ld(Pl + l15 * 40 + quad * 8);  // per-wave, lgkm auto

    if (tk == 127) { WAITV(0); } else { WAITV(8); }  // V(tk) landed
    BAR();

    // ---- PV: O[qrow][e] += P(16x32) @ V(32x512) ----
#pragma unroll
    for (int oc = 0; oc < 32; ++oc) {
      bf16x8 vb = frag_ld(RB + (oc * 16 + l15) * 32 + quad * 8);
      o[oc] = MFMA(pa, vb, o[oc]);
    }
    BAR();  // all waves done reading Vs
    if (tk < 127) STAGE_V(tk + 1);  // flies under next S
  }

  // ---- normalize O, park bf16 in Os[64][520] (overlays RA+RB) ----
  {
    float inv[4];
#pragma unroll
    for (int r = 0; r < 4; ++r) inv[r] = 1.0f / lrow[r];
#pragma unroll
    for (int oc = 0; oc < 32; ++oc) {
#pragma unroll
      for (int r = 0; r < 4; ++r) {
        int row = wave * 16 + quad * 4 + r;
        lds[row * 520 + oc * 16 + l15] = (short)fb(o[oc][r] * inv[r]);
      }
    }
  }
  __syncthreads();

  // ---- out-projection: D[m=cc][n=t] = w_out @ O^T, + bias + residual ----
  f32x4 oa[8][4];
#pragma unroll
  for (int i = 0; i < 8; ++i) {
#pragma unroll
    for (int j = 0; j < 4; ++j) oa[i][j] = {0.f, 0.f, 0.f, 0.f};
  }
  for (int kc = 0; kc < 16; ++kc) {
    bf16x8 ob0 = frag_ld(lds + (l15)*520 + kc * 32 + quad * 8);
    bf16x8 ob1 = frag_ld(lds + (16 + l15) * 520 + kc * 32 + quad * 8);
    bf16x8 ob2 = frag_ld(lds + (32 + l15) * 520 + kc * 32 + quad * 8);
    bf16x8 ob3 = frag_ld(lds + (48 + l15) * 520 + kc * 32 + quad * 8);
#pragma unroll
    for (int es = 0; es < 8; ++es) {
      bf16x8 a = wfrag(w_out, (size_t)(wave * 128 + es * 16 + l15) * 512 + kc * 32 + quad * 8, f32);
      oa[es][0] = MFMA(a, ob0, oa[es][0]);
      oa[es][1] = MFMA(a, ob1, oa[es][1]);
      oa[es][2] = MFMA(a, ob2, oa[es][2]);
      oa[es][3] = MFMA(a, ob3, oa[es][3]);
    }
  }
#pragma unroll
  for (int es = 0; es < 8; ++es) {
    int cc = wave * 128 + es * 16 + quad * 4;
    float b0 = ld(b_out, cc, f32), b1 = ld(b_out, cc + 1, f32);
    float b2 = ld(b_out, cc + 2, f32), b3 = ld(b_out, cc + 3, f32);
#pragma unroll
    for (int ts = 0; ts < 4; ++ts) {
      int t = t0 + ts * 16 + l15;
      float vr[4] = {oa[es][ts][0] + b0, oa[es][ts][1] + b1,
                     oa[es][ts][2] + b2, oa[es][ts][3] + b3};
#pragma unroll
      for (int r = 0; r < 4; ++r) {
        size_t oidx = ((size_t)(nn * C + cc + r) << 12) + t;
        float v = vr[r] + ld(x, oidx, f32);
        if (f32)
          ((float*)out)[oidx] = v;
        else
          ((unsigned short*)out)[oidx] = fb(v);
      }
    }
  }
}

// ---------------------------------------------------------------------------
extern "C" void kernel_launch(void* const* d_in, const int* in_sizes, int n_in,
                              void* d_out, int out_size, void* d_ws, size_t ws_size,
                              hipStream_t stream) {
  const void* x = d_in[0];
  const void* gn_scale = d_in[1];
  const void* gn_bias = d_in[2];
  const void* w_in = d_in[3];
  const void* b_in = d_in[4];
  const void* w_out = d_in[5];
  const void* b_out = d_in[6];
  (void)in_sizes; (void)n_in; (void)out_size;

  // ws: [stats 1KB | per-batch slot 8MB: K swizzled [t][512] + V tiled]
  float* stats = (float*)d_ws;
  unsigned short* kv0 = (unsigned short*)((char*)d_ws + 1024);
  const size_t need4 = 1024 + (size_t)4 * 4194304 * 2;

  gn_stats_kernel<<<NBATCH * GROUPS, 256, 0, stream>>>(x, w_in, stats);

  if (ws_size >= need4) {
    kv_gemm_kernel<<<dim3(4, 128, 4), 256, 0, stream>>>(
        x, gn_scale, gn_bias, stats, w_in, b_in, kv0, 0);
    flash64_kernel<<<dim3(256), 256, 0, stream>>>(
        x, gn_scale, gn_bias, stats, w_in, b_in, kv0, w_out, b_out, d_out, 0, 1);
  } else {
    for (int nn = 0; nn < NBATCH; ++nn) {
      kv_gemm_kernel<<<dim3(4, 128, 1), 256, 0, stream>>>(
          x, gn_scale, gn_bias, stats, w_in, b_in, kv0, nn);
      flash64_kernel<<<dim3(64), 256, 0, stream>>>(
          x, gn_scale, gn_bias, stats, w_in, b_in, kv0, w_out, b_out, d_out, nn, 0);
    }
  }
}

// Round 3
// 821.079 us; speedup vs baseline: 19.0816x; 1.2960x over previous
//
#include <hip/hip_runtime.h>
#include <hip/hip_bf16.h>

// n=4, c=512, h=w=64. Runtime dtype via detect_f32 (R3-proven).
#define NBATCH 4
#define C 512
#define HW 4096
#define GROUPS 32
#define EPSV 1e-5f
#define ATTN_SCALE 0.044194173824159216f  // 1/sqrt(512)

typedef short bf16x8 __attribute__((ext_vector_type(8)));  // 8 bf16 = 4 VGPR
typedef float f32x4 __attribute__((ext_vector_type(4)));

__device__ __forceinline__ float bf(unsigned short u) {
  return __uint_as_float(((unsigned)u) << 16);
}
__device__ __forceinline__ unsigned short fb(float v) {
  __hip_bfloat16 h = __float2bfloat16(v);
  return *(unsigned short*)&h;
}
__device__ __forceinline__ bf16x8 frag_ld(const short* p) {
  return *(const bf16x8*)p;  // 16B-aligned by construction
}
#define MFMA(a, b, c) __builtin_amdgcn_mfma_f32_16x16x32_bf16((a), (b), (c), 0, 0, 0)

#define SCHED_FENCE() __builtin_amdgcn_sched_barrier(0)
// raw barrier (NO vmcnt drain) + compiler/scheduler fences (rule #18 / m152)
#define BAR()                                   \
  do {                                          \
    asm volatile("" ::: "memory");              \
    SCHED_FENCE();                              \
    __builtin_amdgcn_s_barrier();               \
    SCHED_FENCE();                              \
    asm volatile("" ::: "memory");              \
  } while (0)
#define WAITV(N)                                                  \
  do {                                                            \
    asm volatile("s_waitcnt vmcnt(" #N ")" ::: "memory");         \
    SCHED_FENCE();                                                \
  } while (0)

// async global->LDS, 16B per lane; LDS dest is wave-uniform base + lane*16
__device__ __forceinline__ void gl_lds16(const short* g, short* l) {
  __builtin_amdgcn_global_load_lds(
      (const __attribute__((address_space(1))) unsigned int*)g,
      (__attribute__((address_space(3))) unsigned int*)l, 16, 0, 0);
}

__device__ __forceinline__ void unpack8(uint4 w, float* f) {
  f[0] = __uint_as_float(w.x << 16);
  f[1] = __uint_as_float(w.x & 0xFFFF0000u);
  f[2] = __uint_as_float(w.y << 16);
  f[3] = __uint_as_float(w.y & 0xFFFF0000u);
  f[4] = __uint_as_float(w.z << 16);
  f[5] = __uint_as_float(w.z & 0xFFFF0000u);
  f[6] = __uint_as_float(w.w << 16);
  f[7] = __uint_as_float(w.w & 0xFFFF0000u);
}

// Runtime dtype detection (R3-proven).
__device__ __forceinline__ bool detect_f32(const void* w_in) {
  const unsigned short* u = (const unsigned short*)w_in;
  bool f32 = false;
#pragma unroll
  for (int i = 0; i < 64; ++i) {
    float v = bf(u[i]);
    if (!(fabsf(v) < 1e3f)) f32 = true;  // NaN -> true
  }
  return f32;
}
__device__ __forceinline__ float ld(const void* p, size_t i, bool f32) {
  if (f32) return ((const float*)p)[i];
  return bf(((const unsigned short*)p)[i]);
}

// MFMA A-fragment (8 contiguous k-elements) from a weight matrix, either dtype.
__device__ __forceinline__ bf16x8 wfrag(const void* w, size_t off, bool f32) {
  if (f32) {
    const float4* p = (const float4*)((const float*)w + off);
    float4 w0 = p[0], w1 = p[1];
    bf16x8 r;
    r[0] = (short)fb(w0.x); r[1] = (short)fb(w0.y);
    r[2] = (short)fb(w0.z); r[3] = (short)fb(w0.w);
    r[4] = (short)fb(w1.x); r[5] = (short)fb(w1.y);
    r[6] = (short)fb(w1.z); r[7] = (short)fb(w1.w);
    return r;
  }
  return frag_ld((const short*)w + off);
}

// Stage GN-normalized x rows [t0, t0+32) into xn[32][520] (bf16). R3-proven.
__device__ __forceinline__ void stage_xn(short* xn, const void* x,
                                         const void* gsc, const void* gbi,
                                         const float* stats, int nn, int t0,
                                         bool f32) {
  const int tid = threadIdx.x;
  const int part = tid & 3, crel = tid >> 2;
  for (int c0 = 0; c0 < 512; c0 += 64) {
    int c = c0 + crel;
    float rr = stats[128 + nn * GROUPS + (c >> 4)];
    float mu = stats[nn * GROUPS + (c >> 4)];
    float scl = ld(gsc, c, f32) * rr;
    float sft = ld(gbi, c, f32) - mu * scl;
    float f[8];
    if (f32) {
      const float4* p = (const float4*)((const float*)x +
                                        ((size_t)(nn * C + c) << 12) + t0 + part * 8);
      float4 r0 = p[0], r1 = p[1];
      f[0] = r0.x; f[1] = r0.y; f[2] = r0.z; f[3] = r0.w;
      f[4] = r1.x; f[5] = r1.y; f[6] = r1.z; f[7] = r1.w;
    } else {
      uint4 raw = *(const uint4*)((const unsigned short*)x +
                                  ((size_t)(nn * C + c) << 12) + t0 + part * 8);
      unpack8(raw, f);
    }
#pragma unroll
    for (int j = 0; j < 8; ++j)
      xn[(part * 8 + j) * 520 + c] = (short)fb(f[j] * scl + sft);
  }
}

// ---------------------------------------------------------------------------
// GroupNorm stats — R3-proven verbatim.
// ---------------------------------------------------------------------------
__global__ __launch_bounds__(256) void gn_stats_kernel(
    const void* __restrict__ x, const void* __restrict__ w_in,
    float* __restrict__ stats) {
  const bool f32 = detect_f32(w_in);
  const int b = blockIdx.x;
  const size_t base = (size_t)b << 16;
  float s = 0.f, ss = 0.f;
  for (int i = threadIdx.x; i < 65536; i += 256) {
    float v = ld(x, base + i, f32);
    s += v;
    ss += v * v;
  }
  __shared__ float rs[256], rq[256];
  rs[threadIdx.x] = s;
  rq[threadIdx.x] = ss;
  __syncthreads();
  for (int off = 128; off > 0; off >>= 1) {
    if (threadIdx.x < off) {
      rs[threadIdx.x] += rs[threadIdx.x + off];
      rq[threadIdx.x] += rq[threadIdx.x + off];
    }
    __syncthreads();
  }
  if (threadIdx.x == 0) {
    float m = rs[0] * (1.0f / 65536.0f);
    float var = rq[0] * (1.0f / 65536.0f) - m * m;
    stats[b] = m;
    stats[128 + b] = rsqrtf(var + EPSV);
  }
}

// ---------------------------------------------------------------------------
// kv_gemm — proven MFMA core. Epilogue writes:
//   K: kbuf[t][col] PRE-SWIZZLED: granule g=e>>3 stored at g^(t&7).
//   V: vbuf tiled [tk][e][32] with granule swizzle: element (e, trel) stored
//      at granule (trel>>3)^((e>>1)&3), offset trel&7  -> flash PV
//      ds_read_b128 becomes 2-way (free) instead of 8-way conflicted.
// ---------------------------------------------------------------------------
__global__ __launch_bounds__(256) void kv_gemm_kernel(
    const void* __restrict__ x, const void* __restrict__ gsc,
    const void* __restrict__ gbi, const float* __restrict__ stats,
    const void* __restrict__ w_in, const void* __restrict__ b_in,
    unsigned short* __restrict__ kvbase, int nn0) {
  const bool f32 = detect_f32(w_in);
  const int nn = nn0 + blockIdx.z;
  unsigned short* kbuf = kvbase + (size_t)blockIdx.z * 4194304;
  unsigned short* vbuf = kbuf + 2097152;
  __shared__ __align__(16) short xn[32 * 520];
  const int tid = threadIdx.x;
  const int wave = tid >> 6, lane = tid & 63, l15 = lane & 15, quad = lane >> 4;
  const int t0 = blockIdx.y * 32;
  const int proj = blockIdx.x >> 1;  // 0 = K, 1 = V
  const int ehalf = blockIdx.x & 1;

  stage_xn(xn, x, gsc, gbi, stats, nn, t0, f32);
  __syncthreads();

  const int wrow = 512 + proj * 512 + ehalf * 256 + wave * 64;  // w_in row
  const int cbase = ehalf * 256 + wave * 64;                    // col in [0,512)

  f32x4 acc[4][2];
#pragma unroll
  for (int i = 0; i < 4; ++i) {
    acc[i][0] = {0.f, 0.f, 0.f, 0.f};
    acc[i][1] = {0.f, 0.f, 0.f, 0.f};
  }

  for (int kc = 0; kc < 16; ++kc) {
    bf16x8 b0f = frag_ld(xn + l15 * 520 + kc * 32 + quad * 8);
    bf16x8 b1f = frag_ld(xn + (16 + l15) * 520 + kc * 32 + quad * 8);
#pragma unroll
    for (int es = 0; es < 4; ++es) {
      bf16x8 a = wfrag(w_in, (size_t)(wrow + es * 16 + l15) * 512 + kc * 32 + quad * 8, f32);
      acc[es][0] = MFMA(a, b0f, acc[es][0]);
      acc[es][1] = MFMA(a, b1f, acc[es][1]);
    }
  }

#pragma unroll
  for (int es = 0; es < 4; ++es) {
    int bidx = wrow + es * 16 + quad * 4;
    float b0 = ld(b_in, bidx, f32), b1 = ld(b_in, bidx + 1, f32);
    float b2 = ld(b_in, bidx + 2, f32), b3 = ld(b_in, bidx + 3, f32);
    int ecol = cbase + es * 16 + quad * 4;
#pragma unroll
    for (int ts = 0; ts < 2; ++ts) {
      int t = t0 + ts * 16 + l15;
      float vr[4] = {acc[es][ts][0] + b0, acc[es][ts][1] + b1,
                     acc[es][ts][2] + b2, acc[es][ts][3] + b3};
      if (proj == 0) {
        int sw = (((ecol >> 3) ^ (t & 7)) << 3) | (ecol & 7);
        uint2 u;
        u.x = (unsigned)fb(vr[0]) | ((unsigned)fb(vr[1]) << 16);
        u.y = (unsigned)fb(vr[2]) | ((unsigned)fb(vr[3]) << 16);
        *(uint2*)(kbuf + (size_t)t * 512 + sw) = u;
      } else {
        size_t tb = (size_t)(t >> 5) * 16384;
        int trel = t & 31;
#pragma unroll
        for (int i = 0; i < 4; ++i) {
          int e = ecol + i;
          vbuf[tb + (size_t)e * 32 + ((((trel >> 3) ^ ((e >> 1) & 3)) << 3)) +
               (trel & 7)] = fb(vr[i]);
        }
      }
    }
  }
}

// ---------------------------------------------------------------------------
// flash32 — 32 q-rows/block, grid 512 -> 2 blocks/CU (LDS 71.7KB, 2x143KB
// fits 160KB). 4 waves: wave = (col-half ch = wave>>1, row-half rh = wave&1).
// Wave computes S[rh*16..+16][0..32) (2x redundant across col-halves; MFMA is
// cheap at 8% util) and owns O[rh rows][ch*256..+256) (o[16] = 64 VGPR).
// K tile staged via global_load_lds from pre-swizzled kbuf; V tile granule-
// swizzled (2-way banks). Counted vmcnt(8) + raw s_barrier pipeline (proven).
// Softmax: per-lane partial l (single end reduce) + EXACT defer-rescale
// (skip O-rescale unless __any(vmax > mrow); ~5 rescales in 128 tiles).
// ---------------------------------------------------------------------------
__global__ __launch_bounds__(256, 2) void flash32_kernel(
    const void* __restrict__ x, const void* __restrict__ gsc,
    const void* __restrict__ gbi, const float* __restrict__ stats,
    const void* __restrict__ w_in, const void* __restrict__ b_in,
    const unsigned short* __restrict__ kvbase,
    const void* __restrict__ w_out, const void* __restrict__ b_out,
    void* __restrict__ out, int nn0, int conc) {
  const bool f32 = detect_f32(w_in);
  int nn, t0, slot;
  if (conc) {
    int xcd = blockIdx.x & 7;
    nn = xcd >> 1;
    slot = nn;
    t0 = ((((xcd & 1) << 6) | (blockIdx.x >> 3))) << 5;
  } else {
    nn = nn0; slot = 0; t0 = blockIdx.x << 5;
  }
  const unsigned short* kbuf = kvbase + (size_t)slot * 4194304;
  const unsigned short* vbuf = kbuf + 2097152;

  __shared__ __align__(16) short lds[35840];  // 71680 B
  short* RA = lds;                 // xn (Q phase) -> Ktile -> O park
  short* RB = lds + 16640;         // Qs (Q phase) -> Vtile
  const int tid = threadIdx.x;
  const int wave = tid >> 6, lane = tid & 63, l15 = lane & 15, quad = lane >> 4;
  short* Pl = lds + 33280 + wave * 640;  // per-wave P [16][40]
  const int rh = wave & 1;   // row half: q-rows rh*16..+16
  const int ch = wave >> 1;  // col half: O-cols ch*256..+256

  // ================= Q phase (single 32-row tile) =================
  bf16x8 q[16];  // wave's 16 q-rows x 512 k, A-frag layout
  stage_xn(RA, x, gsc, gbi, stats, nn, t0, f32);
  __syncthreads();
  {
    f32x4 qacc[8][2];
#pragma unroll
    for (int i = 0; i < 8; ++i) {
      qacc[i][0] = {0.f, 0.f, 0.f, 0.f};
      qacc[i][1] = {0.f, 0.f, 0.f, 0.f};
    }
    for (int kc = 0; kc < 16; ++kc) {
      bf16x8 bx0 = frag_ld(RA + l15 * 520 + kc * 32 + quad * 8);
      bf16x8 bx1 = frag_ld(RA + (16 + l15) * 520 + kc * 32 + quad * 8);
#pragma unroll
      for (int es = 0; es < 8; ++es) {
        bf16x8 a = wfrag(w_in, (size_t)(wave * 128 + es * 16 + l15) * 512 + kc * 32 + quad * 8, f32);
        qacc[es][0] = MFMA(a, bx0, qacc[es][0]);
        qacc[es][1] = MFMA(a, bx1, qacc[es][1]);
      }
    }
    // D[m=e][n=t] -> Qs[t][e] = (acc + b_in[e]) * ATTN_SCALE (bf16)
#pragma unroll
    for (int es = 0; es < 8; ++es) {
      int e0 = wave * 128 + es * 16 + quad * 4;
      float b0 = ld(b_in, e0, f32), b1 = ld(b_in, e0 + 1, f32);
      float b2 = ld(b_in, e0 + 2, f32), b3 = ld(b_in, e0 + 3, f32);
#pragma unroll
      for (int ts = 0; ts < 2; ++ts) {
        int t = ts * 16 + l15;
        uint2 u;
        u.x = (unsigned)fb((qacc[es][ts][0] + b0) * ATTN_SCALE) |
              ((unsigned)fb((qacc[es][ts][1] + b1) * ATTN_SCALE) << 16);
        u.y = (unsigned)fb((qacc[es][ts][2] + b2) * ATTN_SCALE) |
              ((unsigned)fb((qacc[es][ts][3] + b3) * ATTN_SCALE) << 16);
        *(uint2*)(RB + t * 520 + e0) = u;
      }
    }
    __syncthreads();
#pragma unroll
    for (int kc = 0; kc < 16; ++kc)
      q[kc] = frag_ld(RB + (rh * 16 + l15) * 520 + kc * 32 + quad * 8);
    __syncthreads();
  }

// ================= K/V tile staging macros =================
// per wave: 8 x 1KB global_load_lds, linear copy of its quarter
#define STAGE_K(tk)                                                           \
  {                                                                           \
    const short* s_ = (const short*)kbuf + (size_t)(tk)*16384 + wave * 4096 + \
                      lane * 8;                                               \
    short* d_ = RA + wave * 4096;                                             \
    _Pragma("unroll") for (int i_ = 0; i_ < 8; ++i_)                          \
        gl_lds16(s_ + i_ * 512, d_ + i_ * 512);                               \
  }
#define STAGE_V(tk)                                                           \
  {                                                                           \
    const short* s_ = (const short*)vbuf + (size_t)(tk)*16384 + wave * 4096 + \
                      lane * 8;                                               \
    short* d_ = RB + wave * 4096;                                             \
    _Pragma("unroll") for (int i_ = 0; i_ < 8; ++i_)                          \
        gl_lds16(s_ + i_ * 512, d_ + i_ * 512);                               \
  }

  f32x4 o[16];
#pragma unroll
  for (int oc = 0; oc < 16; ++oc) o[oc] = {0.f, 0.f, 0.f, 0.f};
  float mrow[4], lpart[4];
#pragma unroll
  for (int r = 0; r < 4; ++r) {
    mrow[r] = -3.0e38f;
    lpart[r] = 0.f;
  }

  STAGE_K(0);
  STAGE_V(0);

  for (int tk = 0; tk < 128; ++tk) {
    WAITV(8);  // K(tk) landed (V(tk) may still fly)
    BAR();

    // ---- S = Qw(16x512) @ K^T(32x512): D[m=qrow][n=t] ----
    f32x4 s0 = {0.f, 0.f, 0.f, 0.f}, s1 = {0.f, 0.f, 0.f, 0.f};
#pragma unroll
    for (int kc = 0; kc < 16; ++kc) {
      int g = ((kc * 4 + quad) ^ (l15 & 7)) * 8;  // inverse of kbuf swizzle
      bf16x8 kb0 = frag_ld(RA + l15 * 512 + g);
      bf16x8 kb1 = frag_ld(RA + (16 + l15) * 512 + g);
      s0 = MFMA(q[kc], kb0, s0);
      s1 = MFMA(q[kc], kb1, s1);
    }
    BAR();  // all waves done reading Ktile
    if (tk < 127) STAGE_K(tk + 1);  // flies under softmax + PV

    // ---- online softmax: max-reduce only; per-lane partial l ----
    float vmax[4];
#pragma unroll
    for (int r = 0; r < 4; ++r) {
      float v = fmaxf(s0[r], s1[r]);
      v = fmaxf(v, __shfl_xor(v, 1));
      v = fmaxf(v, __shfl_xor(v, 2));
      v = fmaxf(v, __shfl_xor(v, 4));
      v = fmaxf(v, __shfl_xor(v, 8));
      vmax[r] = v;
    }
    int grow = (vmax[0] > mrow[0]) | (vmax[1] > mrow[1]) |
               (vmax[2] > mrow[2]) | (vmax[3] > mrow[3]);
    if (__any(grow)) {  // exact: skip is legal only when no row max grew
      float pscl[4];
#pragma unroll
      for (int r = 0; r < 4; ++r) {
        float mnew = fmaxf(mrow[r], vmax[r]);
        pscl[r] = __expf(mrow[r] - mnew);
        mrow[r] = mnew;
        lpart[r] *= pscl[r];
      }
#pragma unroll
      for (int oc = 0; oc < 16; ++oc) {
#pragma unroll
        for (int r = 0; r < 4; ++r) o[oc][r] *= pscl[r];
      }
    }
#pragma unroll
    for (int r = 0; r < 4; ++r) {
      float pa_ = __expf(s0[r] - mrow[r]);
      float pb_ = __expf(s1[r] - mrow[r]);
      lpart[r] += pa_ + pb_;
      int row = quad * 4 + r;
      Pl[row * 40 + l15] = (short)fb(pa_);
      Pl[row * 40 + 16 + l15] = (short)fb(pb_);
    }
    bf16x8 pa = frag_ld(Pl + l15 * 40 + quad * 8);  // per-wave, lgkm auto

    if (tk == 127) { WAITV(0); } else { WAITV(8); }  // V(tk) landed
    BAR();

    // ---- PV: O[qrow][e] += P(16x32) @ V(32x256 of this col-half) ----
#pragma unroll
    for (int oc = 0; oc < 16; ++oc) {
      int e = ch * 256 + oc * 16 + l15;
      bf16x8 vb = frag_ld(RB + e * 32 + ((quad ^ ((l15 >> 1) & 3)) << 3));
      o[oc] = MFMA(pa, vb, o[oc]);
    }
    BAR();  // all waves done reading Vtile
    if (tk < 127) STAGE_V(tk + 1);  // flies under next S
  }

  // ---- final l reduce (once, not per tile), normalize, park in RA ----
  {
    float inv[4];
#pragma unroll
    for (int r = 0; r < 4; ++r) {
      float s_ = lpart[r];
      s_ += __shfl_xor(s_, 1);
      s_ += __shfl_xor(s_, 2);
      s_ += __shfl_xor(s_, 4);
      s_ += __shfl_xor(s_, 8);
      inv[r] = 1.0f / s_;
    }
#pragma unroll
    for (int oc = 0; oc < 16; ++oc) {
#pragma unroll
      for (int r = 0; r < 4; ++r) {
        int row = rh * 16 + quad * 4 + r;
        lds[row * 520 + ch * 256 + oc * 16 + l15] = (short)fb(o[oc][r] * inv[r]);
      }
    }
  }
  __syncthreads();

  // ---- out-projection: D[m=cc][n=t] = w_out @ O^T, + bias + residual ----
  f32x4 oa[8][2];
#pragma unroll
  for (int i = 0; i < 8; ++i) {
    oa[i][0] = {0.f, 0.f, 0.f, 0.f};
    oa[i][1] = {0.f, 0.f, 0.f, 0.f};
  }
  for (int kc = 0; kc < 16; ++kc) {
    bf16x8 ob0 = frag_ld(lds + l15 * 520 + kc * 32 + quad * 8);
    bf16x8 ob1 = frag_ld(lds + (16 + l15) * 520 + kc * 32 + quad * 8);
#pragma unroll
    for (int es = 0; es < 8; ++es) {
      bf16x8 a = wfrag(w_out, (size_t)(wave * 128 + es * 16 + l15) * 512 + kc * 32 + quad * 8, f32);
      oa[es][0] = MFMA(a, ob0, oa[es][0]);
      oa[es][1] = MFMA(a, ob1, oa[es][1]);
    }
  }
#pragma unroll
  for (int es = 0; es < 8; ++es) {
    int cc = wave * 128 + es * 16 + quad * 4;
    float b0 = ld(b_out, cc, f32), b1 = ld(b_out, cc + 1, f32);
    float b2 = ld(b_out, cc + 2, f32), b3 = ld(b_out, cc + 3, f32);
#pragma unroll
    for (int ts = 0; ts < 2; ++ts) {
      int t = t0 + ts * 16 + l15;
      float vr[4] = {oa[es][ts][0] + b0, oa[es][ts][1] + b1,
                     oa[es][ts][2] + b2, oa[es][ts][3] + b3};
#pragma unroll
      for (int r = 0; r < 4; ++r) {
        size_t oidx = ((size_t)(nn * C + cc + r) << 12) + t;
        float v = vr[r] + ld(x, oidx, f32);
        if (f32)
          ((float*)out)[oidx] = v;
        else
          ((unsigned short*)out)[oidx] = fb(v);
      }
    }
  }
}

// ---------------------------------------------------------------------------
extern "C" void kernel_launch(void* const* d_in, const int* in_sizes, int n_in,
                              void* d_out, int out_size, void* d_ws, size_t ws_size,
                              hipStream_t stream) {
  const void* x = d_in[0];
  const void* gn_scale = d_in[1];
  const void* gn_bias = d_in[2];
  const void* w_in = d_in[3];
  const void* b_in = d_in[4];
  const void* w_out = d_in[5];
  const void* b_out = d_in[6];
  (void)in_sizes; (void)n_in; (void)out_size;

  // ws: [stats 1KB | per-batch slot 8MB: K swizzled [t][512] + V tiled/swz]
  float* stats = (float*)d_ws;
  unsigned short* kv0 = (unsigned short*)((char*)d_ws + 1024);
  const size_t need4 = 1024 + (size_t)4 * 4194304 * 2;

  gn_stats_kernel<<<NBATCH * GROUPS, 256, 0, stream>>>(x, w_in, stats);

  if (ws_size >= need4) {
    kv_gemm_kernel<<<dim3(4, 128, 4), 256, 0, stream>>>(
        x, gn_scale, gn_bias, stats, w_in, b_in, kv0, 0);
    flash32_kernel<<<dim3(512), 256, 0, stream>>>(
        x, gn_scale, gn_bias, stats, w_in, b_in, kv0, w_out, b_out, d_out, 0, 1);
  } else {
    for (int nn = 0; nn < NBATCH; ++nn) {
      kv_gemm_kernel<<<dim3(4, 128, 1), 256, 0, stream>>>(
          x, gn_scale, gn_bias, stats, w_in, b_in, kv0, nn);
      flash32_kernel<<<dim3(128), 256, 0, stream>>>(
          x, gn_scale, gn_bias, stats, w_in, b_in, kv0, w_out, b_out, d_out, nn, 0);
    }
  }
}